// Round 2
// baseline (2048.140 us; speedup 1.0000x reference)
//
#include <hip/hip_runtime.h>

#define LRELU(a) ((a) > 0.f ? (a) : 0.2f * (a))

// ---------- block-wide inclusive scan helper (256 threads, 4 waves) ----------
__device__ __forceinline__ int blockScanIncl256(int v, int* wl) {
  int t = threadIdx.x, lane = t & 63, w = t >> 6;
  int x = v;
#pragma unroll
  for (int o = 1; o < 64; o <<= 1) {
    int tmp = __shfl_up(x, (unsigned)o, 64);
    if (lane >= o) x += tmp;
  }
  if (lane == 63) wl[w] = x;
  __syncthreads();
  if (t == 0) {
    int s = 0;
#pragma unroll
    for (int j = 0; j < 4; ++j) { int tv = wl[j]; wl[j] = s; s += tv; }
  }
  __syncthreads();
  return x + wl[w];
}

// ---------- CSR build ----------
__global__ __launch_bounds__(256) void k_deg(const int* __restrict__ dst,
                                             int* __restrict__ deg, int E) {
  int e = blockIdx.x * 256 + threadIdx.x;
  if (e < E) atomicAdd(&deg[dst[e]], 1);
}

__global__ __launch_bounds__(256) void k_chunksum(const int* __restrict__ deg,
                                                  int* __restrict__ bsum, int n) {
  __shared__ int wl[4];
  int i = blockIdx.x * 256 + threadIdx.x;
  int v = (i < n) ? deg[i] : 0;
#pragma unroll
  for (int o = 1; o < 64; o <<= 1) v += __shfl_xor(v, o, 64);
  int lane = threadIdx.x & 63, w = threadIdx.x >> 6;
  if (lane == 0) wl[w] = v;
  __syncthreads();
  if (threadIdx.x == 0) bsum[blockIdx.x] = wl[0] + wl[1] + wl[2] + wl[3];
}

// single block; requires nb <= 256 (N <= 65536)
__global__ __launch_bounds__(256) void k_bscan(int* __restrict__ bsum, int nb,
                                               int* __restrict__ csr_off, int n) {
  __shared__ int wl[4];
  int t = threadIdx.x;
  int v = (t < nb) ? bsum[t] : 0;
  int incl = blockScanIncl256(v, wl);
  if (t < nb) bsum[t] = incl - v;  // exclusive block offsets
  if (t == 255) csr_off[n] = incl; // grand total
}

__global__ __launch_bounds__(256) void k_chunkscan(const int* __restrict__ deg,
                                                   const int* __restrict__ bsum,
                                                   int* __restrict__ csr_off,
                                                   int* __restrict__ fill, int n) {
  __shared__ int wl[4];
  int i = blockIdx.x * 256 + threadIdx.x;
  int v = (i < n) ? deg[i] : 0;
  int incl = blockScanIncl256(v, wl);
  int o = bsum[blockIdx.x] + incl - v;
  if (i < n) { csr_off[i] = o; fill[i] = o; }
}

__global__ __launch_bounds__(256) void k_scatter(const int* __restrict__ dst,
                                                 const int* __restrict__ src,
                                                 int* __restrict__ fill,
                                                 int* __restrict__ csr_edges,
                                                 int* __restrict__ csr_src,
                                                 int* __restrict__ csr_dst, int E) {
  int e = blockIdx.x * 256 + threadIdx.x;
  if (e < E) {
    int d = dst[e];
    int p = atomicAdd(&fill[d], 1);
    csr_edges[p] = e;
    csr_src[p] = src[e];
    csr_dst[p] = d;
  }
}

// ---------- self-loop edge attr = mean of incoming edge attrs ----------
// one wave per node: 64 lanes = 4 edges x 16 dims (coalesced 64B per edge)
__global__ __launch_bounds__(256) void k_loopattr(const int* __restrict__ csr_off,
                                                  const int* __restrict__ csr_edges,
                                                  const float* __restrict__ edge_attr,
                                                  float* __restrict__ loop_attr, int n) {
  int t = threadIdx.x, w = t >> 6, lane = t & 63;
  int node = blockIdx.x * 4 + w;
  if (node >= n) return;
  int sub = lane >> 4, k = lane & 15;
  int s0 = csr_off[node], s1 = csr_off[node + 1];
  float acc = 0.f;
  for (int i = s0 + sub; i < s1; i += 4)
    acc += edge_attr[(size_t)csr_edges[i] * 16 + k];
  acc += __shfl_xor(acc, 16, 64);
  acc += __shfl_xor(acc, 32, 64);
  if (sub == 0) loop_attr[node * 16 + k] = acc / fmaxf((float)(s1 - s0), 1.f);
}

// ---------- layer 1 linear: 8 nodes per wave, W rows from global (L1-resident) ----
__global__ __launch_bounds__(256) void k_lin1(const float* __restrict__ x,
                                              const float* __restrict__ W1,
                                              const float* __restrict__ as1,
                                              const float* __restrict__ ad1,
                                              float* __restrict__ h1,
                                              float* __restrict__ als,
                                              float* __restrict__ ald, int n) {
  int t = threadIdx.x, w = t >> 6, lane = t & 63;
  int base = (blockIdx.x * 4 + w) * 8;
  if (base >= n) return;
  float xa[8], xb[8], acc[8];
#pragma unroll
  for (int j = 0; j < 8; ++j) {
    int r = min(base + j, n - 1);
    xa[j] = x[(size_t)r * 128 + lane];
    xb[j] = x[(size_t)r * 128 + 64 + lane];
    acc[j] = 0.f;
  }
#pragma unroll
  for (int kk = 0; kk < 64; ++kk) {
    float wv = W1[kk * 64 + lane];
#pragma unroll
    for (int j = 0; j < 8; ++j)
      acc[j] = fmaf(__shfl(xa[j], kk, 64), wv, acc[j]);
  }
#pragma unroll
  for (int kk = 0; kk < 64; ++kk) {
    float wv = W1[(64 + kk) * 64 + lane];
#pragma unroll
    for (int j = 0; j < 8; ++j)
      acc[j] = fmaf(__shfl(xb[j], kk, 64), wv, acc[j]);
  }
  float asv = as1[lane], adv = ad1[lane];
#pragma unroll
  for (int j = 0; j < 8; ++j) {
    int node = base + j;
    if (node >= n) break;
    h1[(size_t)node * 64 + lane] = acc[j];
    float ps = acc[j] * asv, pd = acc[j] * adv;
#pragma unroll
    for (int o = 1; o < 16; o <<= 1) {
      ps += __shfl_xor(ps, o, 64);
      pd += __shfl_xor(pd, o, 64);
    }
    if ((lane & 15) == 0) {
      als[node * 4 + (lane >> 4)] = ps;
      ald[node * 4 + (lane >> 4)] = pd;
    }
  }
}

// ---------- CSR-ordered fused logits, layer 1: elog[i][h]=LRELU(als[s]+ald[d]+ea@wa)
__global__ __launch_bounds__(256) void k_elog1(const int* __restrict__ csr_edges,
                                               const int* __restrict__ csr_src,
                                               const int* __restrict__ csr_dst,
                                               const float* __restrict__ edge_attr,
                                               const float* __restrict__ loop_attr,
                                               const float* __restrict__ We1,
                                               const float* __restrict__ ae1,
                                               const float* __restrict__ als,
                                               const float* __restrict__ ald,
                                               float* __restrict__ elog,
                                               float* __restrict__ selfl, int E, int n) {
  __shared__ float wa[64];  // [k*4+h] = sum_c We1[k,h*16+c]*ae1[h,c]
  int t = threadIdx.x;
  if (t < 64) {
    int k = t >> 2, hh = t & 3;
    float s = 0.f;
#pragma unroll
    for (int c = 0; c < 16; ++c) s = fmaf(We1[k * 64 + hh * 16 + c], ae1[hh * 16 + c], s);
    wa[t] = s;
  }
  __syncthreads();
  int idx = blockIdx.x * 256 + t;
  if (idx >= E + n) return;
  int s, d;
  const float* ea;
  if (idx < E) {
    s = csr_src[idx]; d = csr_dst[idx];
    ea = edge_attr + (size_t)csr_edges[idx] * 16;
  } else {
    s = d = idx - E;
    ea = loop_attr + (size_t)s * 16;
  }
  float4 av = *(const float4*)(als + (size_t)s * 4);
  float4 dv = *(const float4*)(ald + (size_t)d * 4);
  float l0 = av.x + dv.x, l1 = av.y + dv.y, l2 = av.z + dv.z, l3 = av.w + dv.w;
#pragma unroll
  for (int k = 0; k < 16; ++k) {
    float v = ea[k];
    l0 = fmaf(v, wa[k * 4 + 0], l0);
    l1 = fmaf(v, wa[k * 4 + 1], l1);
    l2 = fmaf(v, wa[k * 4 + 2], l2);
    l3 = fmaf(v, wa[k * 4 + 3], l3);
  }
  float4 r = make_float4(LRELU(l0), LRELU(l1), LRELU(l2), LRELU(l3));
  if (idx < E) *(float4*)(elog + (size_t)idx * 4) = r;
  else *(float4*)(selfl + (size_t)(idx - E) * 4) = r;
}

// ---------- layer 1 aggregation: single sweep, online softmax, 3-stage pipeline ----
__global__ __launch_bounds__(256) void k_agg1(const int* __restrict__ csr_off,
                                              const int* __restrict__ csr_src,
                                              const float* __restrict__ elog,
                                              const float* __restrict__ selfl,
                                              const float* __restrict__ h1,
                                              const float* __restrict__ b1,
                                              float* __restrict__ out1, int n) {
  int t = threadIdx.x, w = t >> 6, lane = t & 63;
  int node = blockIdx.x * 4 + w;
  if (node >= n) return;
  int head = lane >> 4;
  int s0 = csr_off[node], s1 = csr_off[node + 1];
  float mx = selfl[node * 4 + head];
  float den = 1.f;
  float acc = h1[(size_t)node * 64 + lane];  // self-loop contribution at exp(0)
  int n_it = s1 - s0;
  if (n_it > 0) {
    int sA = csr_src[s0];
    float aA = elog[(size_t)s0 * 4 + head];
    int i1 = s0 + min(1, n_it - 1);
    int sB = csr_src[i1];
    float aB = elog[(size_t)i1 * 4 + head];
    float hA = h1[(size_t)sA * 64 + lane];
    for (int k = 0; k < n_it; ++k) {
      int i2 = s0 + min(k + 2, n_it - 1);
      int sC = csr_src[i2];
      float aC = elog[(size_t)i2 * 4 + head];
      float hB = h1[(size_t)sB * 64 + lane];
      float nm = fmaxf(mx, aA);
      float corr = __expf(mx - nm);
      float ex = __expf(aA - nm);
      den = den * corr + ex;
      acc = fmaf(ex, hA, acc * corr);
      mx = nm;
      aA = aB; aB = aC; sB = sC; hA = hB;
    }
  }
  float r = acc / den + b1[lane];
  out1[(size_t)node * 64 + lane] = r > 0.f ? r : expm1f(r);  // ELU fused
}

// ---------- layer 2 linear: 8 nodes per wave ----------
__global__ __launch_bounds__(256) void k_lin2(const float* __restrict__ xin,
                                              const float* __restrict__ W2,
                                              const float* __restrict__ as2,
                                              const float* __restrict__ ad2,
                                              float* __restrict__ h2,
                                              float* __restrict__ als,
                                              float* __restrict__ ald, int n) {
  int t = threadIdx.x, w = t >> 6, lane = t & 63;
  int base = (blockIdx.x * 4 + w) * 8;
  if (base >= n) return;
  float xa[8], acc[8];
#pragma unroll
  for (int j = 0; j < 8; ++j) {
    int r = min(base + j, n - 1);
    xa[j] = xin[(size_t)r * 64 + lane];
    acc[j] = 0.f;
  }
#pragma unroll
  for (int kk = 0; kk < 64; ++kk) {
    float wv = W2[kk * 64 + lane];
#pragma unroll
    for (int j = 0; j < 8; ++j)
      acc[j] = fmaf(__shfl(xa[j], kk, 64), wv, acc[j]);
  }
  float asv = as2[lane], adv = ad2[lane];
#pragma unroll
  for (int j = 0; j < 8; ++j) {
    int node = base + j;
    if (node >= n) break;
    h2[(size_t)node * 64 + lane] = acc[j];
    float ps = acc[j] * asv, pd = acc[j] * adv;
#pragma unroll
    for (int o = 1; o < 64; o <<= 1) {
      ps += __shfl_xor(ps, o, 64);
      pd += __shfl_xor(pd, o, 64);
    }
    if (lane == 0) { als[node] = ps; ald[node] = pd; }
  }
}

// ---------- CSR-ordered fused logits, layer 2 (H=1, scalar) ----------
__global__ __launch_bounds__(256) void k_elog2(const int* __restrict__ csr_edges,
                                               const int* __restrict__ csr_src,
                                               const int* __restrict__ csr_dst,
                                               const float* __restrict__ edge_attr,
                                               const float* __restrict__ loop_attr,
                                               const float* __restrict__ We2,
                                               const float* __restrict__ ae2,
                                               const float* __restrict__ als,
                                               const float* __restrict__ ald,
                                               float* __restrict__ elog,
                                               float* __restrict__ selfl, int E, int n) {
  __shared__ float wa[16];
  int t = threadIdx.x;
  if (t < 16) {
    float s = 0.f;
#pragma unroll
    for (int c = 0; c < 64; ++c) s = fmaf(We2[t * 64 + c], ae2[c], s);
    wa[t] = s;
  }
  __syncthreads();
  int idx = blockIdx.x * 256 + t;
  if (idx >= E + n) return;
  int s, d;
  const float* ea;
  if (idx < E) {
    s = csr_src[idx]; d = csr_dst[idx];
    ea = edge_attr + (size_t)csr_edges[idx] * 16;
  } else {
    s = d = idx - E;
    ea = loop_attr + (size_t)s * 16;
  }
  float lg = als[s] + ald[d];
#pragma unroll
  for (int k = 0; k < 16; ++k) lg = fmaf(ea[k], wa[k], lg);
  lg = LRELU(lg);
  if (idx < E) elog[idx] = lg;
  else selfl[idx - E] = lg;
}

// ---------- layer 2 aggregation ----------
__global__ __launch_bounds__(256) void k_agg2(const int* __restrict__ csr_off,
                                              const int* __restrict__ csr_src,
                                              const float* __restrict__ elog,
                                              const float* __restrict__ selfl,
                                              const float* __restrict__ h2,
                                              const float* __restrict__ b2,
                                              float* __restrict__ out2, int n) {
  int t = threadIdx.x, w = t >> 6, lane = t & 63;
  int node = blockIdx.x * 4 + w;
  if (node >= n) return;
  int s0 = csr_off[node], s1 = csr_off[node + 1];
  float mx = selfl[node];
  float den = 1.f;
  float acc = h2[(size_t)node * 64 + lane];
  int n_it = s1 - s0;
  if (n_it > 0) {
    int sA = csr_src[s0];
    float aA = elog[s0];
    int i1 = s0 + min(1, n_it - 1);
    int sB = csr_src[i1];
    float aB = elog[i1];
    float hA = h2[(size_t)sA * 64 + lane];
    for (int k = 0; k < n_it; ++k) {
      int i2 = s0 + min(k + 2, n_it - 1);
      int sC = csr_src[i2];
      float aC = elog[i2];
      float hB = h2[(size_t)sB * 64 + lane];
      float nm = fmaxf(mx, aA);
      float corr = __expf(mx - nm);
      float ex = __expf(aA - nm);
      den = den * corr + ex;
      acc = fmaf(ex, hA, acc * corr);
      mx = nm;
      aA = aB; aB = aC; sB = sC; hA = hB;
    }
  }
  out2[(size_t)node * 64 + lane] = acc / den + b2[lane];  // H2=1: mean = identity
}

// ---------- pooling: sorted batch, wave handles 64 consecutive nodes ----------
__global__ __launch_bounds__(256) void k_pool(const float* __restrict__ out2,
                                              const int* __restrict__ batch,
                                              float* __restrict__ pooled,
                                              float* __restrict__ cnt, int n) {
  int wgl = blockIdx.x * 4 + (threadIdx.x >> 6);
  int lane = threadIdx.x & 63;
  int i0 = wgl * 64;
  if (i0 >= n) return;
  int i1 = min(i0 + 64, n);
  int cur = -1;
  float acc = 0.f, c = 0.f;
  for (int i = i0; i < i1; ++i) {
    int g = batch[i];
    if (g != cur) {
      if (cur >= 0) {
        atomicAdd(&pooled[cur * 64 + lane], acc);
        if (lane == 0) atomicAdd(&cnt[cur], c);
      }
      cur = g; acc = 0.f; c = 0.f;
    }
    acc += out2[(size_t)i * 64 + lane];
    c += 1.f;
  }
  if (cur >= 0) {
    atomicAdd(&pooled[cur * 64 + lane], acc);
    if (lane == 0) atomicAdd(&cnt[cur], c);
  }
}

// ---------- final: out[g,:] = (pooled[g,:]/cnt[g]) @ Pw + Pb ----------
__global__ __launch_bounds__(64) void k_final(const float* __restrict__ pooled,
                                              const float* __restrict__ cnt,
                                              const float* __restrict__ Pw,
                                              const float* __restrict__ Pb,
                                              float* __restrict__ out) {
  __shared__ float m[64];
  int g = blockIdx.x, o = threadIdx.x;
  m[o] = pooled[g * 64 + o] / fmaxf(cnt[g], 1.f);
  __syncthreads();
  float s = Pb[o];
#pragma unroll
  for (int c = 0; c < 64; ++c) s = fmaf(m[c], Pw[c * 64 + o], s);
  out[g * 64 + o] = s;
}

extern "C" void kernel_launch(void* const* d_in, const int* in_sizes, int n_in,
                              void* d_out, int out_size, void* d_ws, size_t ws_size,
                              hipStream_t stream) {
  const float* x         = (const float*)d_in[0];
  const int*   edge_index= (const int*)d_in[1];
  const float* edge_attr = (const float*)d_in[2];
  const int*   batch     = (const int*)d_in[3];
  const float* W1  = (const float*)d_in[4];
  const float* as1 = (const float*)d_in[5];
  const float* ad1 = (const float*)d_in[6];
  const float* We1 = (const float*)d_in[7];
  const float* ae1 = (const float*)d_in[8];
  const float* b1  = (const float*)d_in[9];
  const float* W2  = (const float*)d_in[10];
  const float* as2 = (const float*)d_in[11];
  const float* ad2 = (const float*)d_in[12];
  const float* We2 = (const float*)d_in[13];
  const float* ae2 = (const float*)d_in[14];
  const float* b2  = (const float*)d_in[15];
  const float* Pw  = (const float*)d_in[16];
  const float* Pb  = (const float*)d_in[17];

  const int N = in_sizes[0] / 128;
  const int E = in_sizes[1] / 2;
  const int G = out_size / 64;
  const int* srcI = edge_index;
  const int* dstI = edge_index + E;

  // ---- workspace layout (16B-aligned slots) ----
  float* ws = (float*)d_ws;
  size_t off = 0;
  auto alloc = [&](size_t elems) {
    float* p = ws + off;
    off += (elems + 3) & ~(size_t)3;
    return p;
  };
  int*   deg       = (int*)alloc(N);            // zeroed
  float* cnt       = alloc(G);                  // zeroed
  float* pooled    = alloc((size_t)G * 64);     // zeroed
  size_t zero_bytes = off * sizeof(float);
  int*   csr_off   = (int*)alloc(N + 1);
  int*   fill      = (int*)alloc(N);
  int*   csr_edges = (int*)alloc(E);
  int*   csr_src   = (int*)alloc(E);
  int*   csr_dst   = (int*)alloc(E);
  int*   bsum      = (int*)alloc(1024);
  float* loop_attr = alloc((size_t)N * 16);
  float* h         = alloc((size_t)N * 64);     // h1, reused as h2
  float* als       = alloc((size_t)N * 4);      // layer2 reuses first N
  float* ald       = alloc((size_t)N * 4);
  float* selfl     = alloc((size_t)N * 4);      // layer2 reuses first N
  float* elog      = alloc((size_t)E * 4);      // layer2 reuses first E
  float* outn      = alloc((size_t)N * 64);     // out1, reused as out2

  (void)ws_size; (void)n_in;
  hipMemsetAsync(d_ws, 0, zero_bytes, stream);

  const int ebl  = (E + 255) / 256;
  const int nb   = (N + 255) / 256;
  const int nbl4 = (N + 3) / 4;
  const int nbl32= (N + 31) / 32;
  const int eN   = (E + N + 255) / 256;

  // CSR build (by dst)
  k_deg<<<ebl, 256, 0, stream>>>(dstI, deg, E);
  k_chunksum<<<nb, 256, 0, stream>>>(deg, bsum, N);
  k_bscan<<<1, 256, 0, stream>>>(bsum, nb, csr_off, N);
  k_chunkscan<<<nb, 256, 0, stream>>>(deg, bsum, csr_off, fill, N);
  k_scatter<<<ebl, 256, 0, stream>>>(dstI, srcI, fill, csr_edges, csr_src, csr_dst, E);
  k_loopattr<<<nbl4, 256, 0, stream>>>(csr_off, csr_edges, edge_attr, loop_attr, N);

  // layer 1
  k_lin1<<<nbl32, 256, 0, stream>>>(x, W1, as1, ad1, h, als, ald, N);
  k_elog1<<<eN, 256, 0, stream>>>(csr_edges, csr_src, csr_dst, edge_attr, loop_attr,
                                  We1, ae1, als, ald, elog, selfl, E, N);
  k_agg1<<<nbl4, 256, 0, stream>>>(csr_off, csr_src, elog, selfl, h, b1, outn, N);

  // layer 2 (reuses h/als/ald/selfl/elog slots; out2 overwrites out1)
  k_lin2<<<nbl32, 256, 0, stream>>>(outn, W2, as2, ad2, h, als, ald, N);
  k_elog2<<<eN, 256, 0, stream>>>(csr_edges, csr_src, csr_dst, edge_attr, loop_attr,
                                  We2, ae2, als, ald, elog, selfl, E, N);
  k_agg2<<<nbl4, 256, 0, stream>>>(csr_off, csr_src, elog, selfl, h, b2, outn, N);

  // pool + project
  k_pool<<<((N + 63) / 64 + 3) / 4, 256, 0, stream>>>(outn, batch, pooled, cnt, N);
  k_final<<<G, 64, 0, stream>>>(pooled, cnt, Pw, Pb, (float*)d_out);
}

// Round 3
// 426.762 us; speedup vs baseline: 4.7993x; 4.7993x over previous
//
#include <hip/hip_runtime.h>

#define LRELU(a) ((a) > 0.f ? (a) : 0.2f * (a))

// ---------- block-wide inclusive scan helper (256 threads, 4 waves) ----------
__device__ __forceinline__ int blockScanIncl256(int v, int* wl) {
  int t = threadIdx.x, lane = t & 63, w = t >> 6;
  int x = v;
#pragma unroll
  for (int o = 1; o < 64; o <<= 1) {
    int tmp = __shfl_up(x, (unsigned)o, 64);
    if (lane >= o) x += tmp;
  }
  if (lane == 63) wl[w] = x;
  __syncthreads();
  if (t == 0) {
    int s = 0;
#pragma unroll
    for (int j = 0; j < 4; ++j) { int tv = wl[j]; wl[j] = s; s += tv; }
  }
  __syncthreads();
  return x + wl[w];
}

// ---------- CSR build ----------
__global__ __launch_bounds__(256) void k_deg(const int* __restrict__ dst,
                                             int* __restrict__ deg, int E) {
  int e = blockIdx.x * 256 + threadIdx.x;
  if (e < E) atomicAdd(&deg[dst[e]], 1);
}

__global__ __launch_bounds__(256) void k_chunksum(const int* __restrict__ deg,
                                                  int* __restrict__ bsum, int n) {
  __shared__ int wl[4];
  int i = blockIdx.x * 256 + threadIdx.x;
  int v = (i < n) ? deg[i] : 0;
#pragma unroll
  for (int o = 1; o < 64; o <<= 1) v += __shfl_xor(v, o, 64);
  int lane = threadIdx.x & 63, w = threadIdx.x >> 6;
  if (lane == 0) wl[w] = v;
  __syncthreads();
  if (threadIdx.x == 0) bsum[blockIdx.x] = wl[0] + wl[1] + wl[2] + wl[3];
}

// single block; requires nb <= 256 (N <= 65536)
__global__ __launch_bounds__(256) void k_bscan(int* __restrict__ bsum, int nb,
                                               int* __restrict__ csr_off, int n) {
  __shared__ int wl[4];
  int t = threadIdx.x;
  int v = (t < nb) ? bsum[t] : 0;
  int incl = blockScanIncl256(v, wl);
  if (t < nb) bsum[t] = incl - v;  // exclusive block offsets
  if (t == 255) csr_off[n] = incl; // grand total
}

__global__ __launch_bounds__(256) void k_chunkscan(const int* __restrict__ deg,
                                                   const int* __restrict__ bsum,
                                                   int* __restrict__ csr_off,
                                                   int* __restrict__ fill, int n) {
  __shared__ int wl[4];
  int i = blockIdx.x * 256 + threadIdx.x;
  int v = (i < n) ? deg[i] : 0;
  int incl = blockScanIncl256(v, wl);
  int o = bsum[blockIdx.x] + incl - v;
  if (i < n) { csr_off[i] = o; fill[i] = o; }
}

__global__ __launch_bounds__(256) void k_scatter(const int* __restrict__ dst,
                                                 const int* __restrict__ src,
                                                 int* __restrict__ fill,
                                                 int* __restrict__ csr_edges,
                                                 int* __restrict__ csr_src,
                                                 int* __restrict__ csr_dst, int E) {
  int e = blockIdx.x * 256 + threadIdx.x;
  if (e < E) {
    int d = dst[e];
    int p = atomicAdd(&fill[d], 1);
    csr_edges[p] = e;
    csr_src[p] = src[e];
    csr_dst[p] = d;
  }
}

// ---------- self-loop edge attr = mean of incoming edge attrs ----------
// one wave per node: 64 lanes = 4 edges x 16 dims (coalesced 64B per edge)
__global__ __launch_bounds__(256) void k_loopattr(const int* __restrict__ csr_off,
                                                  const int* __restrict__ csr_edges,
                                                  const float* __restrict__ edge_attr,
                                                  float* __restrict__ loop_attr, int n) {
  int t = threadIdx.x, w = t >> 6, lane = t & 63;
  int node = blockIdx.x * 4 + w;
  if (node >= n) return;
  int sub = lane >> 4, k = lane & 15;
  int s0 = csr_off[node], s1 = csr_off[node + 1];
  float acc = 0.f;
  for (int i = s0 + sub; i < s1; i += 4)
    acc += edge_attr[(size_t)csr_edges[i] * 16 + k];
  acc += __shfl_xor(acc, 16, 64);
  acc += __shfl_xor(acc, 32, 64);
  if (sub == 0) loop_attr[node * 16 + k] = acc / fmaxf((float)(s1 - s0), 1.f);
}

// ---------- tiled f32 GEMM: H[b0:b0+64][0:64] = X[b0:b0+64][0:K] @ W[K][64] ----------
// 256 threads = 16x16, each computes a 4x4 tile. X stride must equal K.
template <int K>
__global__ __launch_bounds__(256) void k_gemm(const float* __restrict__ X,
                                              const float* __restrict__ W,
                                              float* __restrict__ H, int n) {
  __shared__ float Xs[64][K + 4];
  __shared__ float Ws[K][64];
  int t = threadIdx.x;
  int b0 = blockIdx.x * 64;
  for (int i = t; i < K * 64; i += 256) Ws[i >> 6][i & 63] = W[i];
  for (int i = t; i < 64 * K; i += 256) {
    int node = i / K, k = i % K;
    int r = b0 + node;
    Xs[node][k] = (r < n) ? X[(size_t)r * K + k] : 0.f;
  }
  __syncthreads();
  int tx = t & 15, ty = t >> 4;
  float acc[4][4] = {};
#pragma unroll 2
  for (int k4 = 0; k4 < K; k4 += 4) {
    float wvf[4][4];
#pragma unroll
    for (int j = 0; j < 4; ++j)
      *(float4*)&wvf[j][0] = *(const float4*)&Ws[k4 + j][tx * 4];
#pragma unroll
    for (int i = 0; i < 4; ++i) {
      float xvf[4];
      *(float4*)&xvf[0] = *(const float4*)&Xs[ty * 4 + i][k4];
#pragma unroll
      for (int kk = 0; kk < 4; ++kk)
#pragma unroll
        for (int j = 0; j < 4; ++j)
          acc[i][j] = fmaf(xvf[kk], wvf[kk][j], acc[i][j]);
    }
  }
#pragma unroll
  for (int i = 0; i < 4; ++i) {
    int node = b0 + ty * 4 + i;
    if (node < n)
      *(float4*)&H[(size_t)node * 64 + tx * 4] =
          make_float4(acc[i][0], acc[i][1], acc[i][2], acc[i][3]);
  }
}

// ---------- attention coefficients: als/ald[node*H+head] = h[node,head,:] . a ----------
template <int HH>
__global__ __launch_bounds__(256) void k_attn(const float* __restrict__ h,
                                              const float* __restrict__ a_s,
                                              const float* __restrict__ a_d,
                                              float* __restrict__ als,
                                              float* __restrict__ ald, int n) {
  constexpr int C = 64 / HH;
  int idx = blockIdx.x * 256 + threadIdx.x;
  if (idx >= n * HH) return;
  int node = (HH == 1) ? idx : (idx / HH);
  int head = (HH == 1) ? 0 : (idx & (HH - 1));
  const float* hp = h + (size_t)node * 64 + head * C;
  const float* sp = a_s + head * C;
  const float* dp = a_d + head * C;
  float ps = 0.f, pd = 0.f;
#pragma unroll
  for (int c = 0; c < C; c += 4) {
    float4 hv = *(const float4*)(hp + c);
    float4 sv = *(const float4*)(sp + c);
    float4 dv = *(const float4*)(dp + c);
    ps = fmaf(hv.x, sv.x, ps); ps = fmaf(hv.y, sv.y, ps);
    ps = fmaf(hv.z, sv.z, ps); ps = fmaf(hv.w, sv.w, ps);
    pd = fmaf(hv.x, dv.x, pd); pd = fmaf(hv.y, dv.y, pd);
    pd = fmaf(hv.z, dv.z, pd); pd = fmaf(hv.w, dv.w, pd);
  }
  als[idx] = ps;
  ald[idx] = pd;
}

// ---------- CSR-ordered fused logits, layer 1: elog[i][h]=LRELU(als[s]+ald[d]+ea@wa)
__global__ __launch_bounds__(256) void k_elog1(const int* __restrict__ csr_edges,
                                               const int* __restrict__ csr_src,
                                               const int* __restrict__ csr_dst,
                                               const float* __restrict__ edge_attr,
                                               const float* __restrict__ loop_attr,
                                               const float* __restrict__ We1,
                                               const float* __restrict__ ae1,
                                               const float* __restrict__ als,
                                               const float* __restrict__ ald,
                                               float* __restrict__ elog,
                                               float* __restrict__ selfl, int E, int n) {
  __shared__ float wa[64];  // [k*4+h] = sum_c We1[k,h*16+c]*ae1[h,c]
  int t = threadIdx.x;
  if (t < 64) {
    int k = t >> 2, hh = t & 3;
    float s = 0.f;
#pragma unroll
    for (int c = 0; c < 16; ++c) s = fmaf(We1[k * 64 + hh * 16 + c], ae1[hh * 16 + c], s);
    wa[t] = s;
  }
  __syncthreads();
  int idx = blockIdx.x * 256 + t;
  if (idx >= E + n) return;
  int s, d;
  const float* ea;
  if (idx < E) {
    s = csr_src[idx]; d = csr_dst[idx];
    ea = edge_attr + (size_t)csr_edges[idx] * 16;
  } else {
    s = d = idx - E;
    ea = loop_attr + (size_t)s * 16;
  }
  float4 av = *(const float4*)(als + (size_t)s * 4);
  float4 dv = *(const float4*)(ald + (size_t)d * 4);
  float l0 = av.x + dv.x, l1 = av.y + dv.y, l2 = av.z + dv.z, l3 = av.w + dv.w;
#pragma unroll
  for (int k = 0; k < 16; ++k) {
    float v = ea[k];
    l0 = fmaf(v, wa[k * 4 + 0], l0);
    l1 = fmaf(v, wa[k * 4 + 1], l1);
    l2 = fmaf(v, wa[k * 4 + 2], l2);
    l3 = fmaf(v, wa[k * 4 + 3], l3);
  }
  float4 r = make_float4(LRELU(l0), LRELU(l1), LRELU(l2), LRELU(l3));
  if (idx < E) *(float4*)(elog + (size_t)idx * 4) = r;
  else *(float4*)(selfl + (size_t)(idx - E) * 4) = r;
}

// ---------- layer 1 aggregation: single sweep, online softmax, 3-stage pipeline ----
__global__ __launch_bounds__(256) void k_agg1(const int* __restrict__ csr_off,
                                              const int* __restrict__ csr_src,
                                              const float* __restrict__ elog,
                                              const float* __restrict__ selfl,
                                              const float* __restrict__ h1,
                                              const float* __restrict__ b1,
                                              float* __restrict__ out1, int n) {
  int t = threadIdx.x, w = t >> 6, lane = t & 63;
  int node = blockIdx.x * 4 + w;
  if (node >= n) return;
  int head = lane >> 4;
  int s0 = csr_off[node], s1 = csr_off[node + 1];
  float mx = selfl[node * 4 + head];
  float den = 1.f;
  float acc = h1[(size_t)node * 64 + lane];  // self-loop contribution at exp(0)
  int n_it = s1 - s0;
  if (n_it > 0) {
    int sA = csr_src[s0];
    float aA = elog[(size_t)s0 * 4 + head];
    int i1 = s0 + min(1, n_it - 1);
    int sB = csr_src[i1];
    float aB = elog[(size_t)i1 * 4 + head];
    float hA = h1[(size_t)sA * 64 + lane];
    for (int k = 0; k < n_it; ++k) {
      int i2 = s0 + min(k + 2, n_it - 1);
      int sC = csr_src[i2];
      float aC = elog[(size_t)i2 * 4 + head];
      float hB = h1[(size_t)sB * 64 + lane];
      float nm = fmaxf(mx, aA);
      float corr = __expf(mx - nm);
      float ex = __expf(aA - nm);
      den = den * corr + ex;
      acc = fmaf(ex, hA, acc * corr);
      mx = nm;
      aA = aB; aB = aC; sB = sC; hA = hB;
    }
  }
  float r = acc / den + b1[lane];
  out1[(size_t)node * 64 + lane] = r > 0.f ? r : expm1f(r);  // ELU fused
}

// ---------- CSR-ordered fused logits, layer 2 (H=1, scalar) ----------
__global__ __launch_bounds__(256) void k_elog2(const int* __restrict__ csr_edges,
                                               const int* __restrict__ csr_src,
                                               const int* __restrict__ csr_dst,
                                               const float* __restrict__ edge_attr,
                                               const float* __restrict__ loop_attr,
                                               const float* __restrict__ We2,
                                               const float* __restrict__ ae2,
                                               const float* __restrict__ als,
                                               const float* __restrict__ ald,
                                               float* __restrict__ elog,
                                               float* __restrict__ selfl, int E, int n) {
  __shared__ float wa[16];
  int t = threadIdx.x;
  if (t < 16) {
    float s = 0.f;
#pragma unroll
    for (int c = 0; c < 64; ++c) s = fmaf(We2[t * 64 + c], ae2[c], s);
    wa[t] = s;
  }
  __syncthreads();
  int idx = blockIdx.x * 256 + t;
  if (idx >= E + n) return;
  int s, d;
  const float* ea;
  if (idx < E) {
    s = csr_src[idx]; d = csr_dst[idx];
    ea = edge_attr + (size_t)csr_edges[idx] * 16;
  } else {
    s = d = idx - E;
    ea = loop_attr + (size_t)s * 16;
  }
  float lg = als[s] + ald[d];
#pragma unroll
  for (int k = 0; k < 16; ++k) lg = fmaf(ea[k], wa[k], lg);
  lg = LRELU(lg);
  if (idx < E) elog[idx] = lg;
  else selfl[idx - E] = lg;
}

// ---------- layer 2 aggregation ----------
__global__ __launch_bounds__(256) void k_agg2(const int* __restrict__ csr_off,
                                              const int* __restrict__ csr_src,
                                              const float* __restrict__ elog,
                                              const float* __restrict__ selfl,
                                              const float* __restrict__ h2,
                                              const float* __restrict__ b2,
                                              float* __restrict__ out2, int n) {
  int t = threadIdx.x, w = t >> 6, lane = t & 63;
  int node = blockIdx.x * 4 + w;
  if (node >= n) return;
  int s0 = csr_off[node], s1 = csr_off[node + 1];
  float mx = selfl[node];
  float den = 1.f;
  float acc = h2[(size_t)node * 64 + lane];
  int n_it = s1 - s0;
  if (n_it > 0) {
    int sA = csr_src[s0];
    float aA = elog[s0];
    int i1 = s0 + min(1, n_it - 1);
    int sB = csr_src[i1];
    float aB = elog[i1];
    float hA = h2[(size_t)sA * 64 + lane];
    for (int k = 0; k < n_it; ++k) {
      int i2 = s0 + min(k + 2, n_it - 1);
      int sC = csr_src[i2];
      float aC = elog[i2];
      float hB = h2[(size_t)sB * 64 + lane];
      float nm = fmaxf(mx, aA);
      float corr = __expf(mx - nm);
      float ex = __expf(aA - nm);
      den = den * corr + ex;
      acc = fmaf(ex, hA, acc * corr);
      mx = nm;
      aA = aB; aB = aC; sB = sC; hA = hB;
    }
  }
  out2[(size_t)node * 64 + lane] = acc / den + b2[lane];  // H2=1: mean = identity
}

// ---------- pooling: sorted batch, wave handles 64 consecutive nodes ----------
__global__ __launch_bounds__(256) void k_pool(const float* __restrict__ out2,
                                              const int* __restrict__ batch,
                                              float* __restrict__ pooled,
                                              float* __restrict__ cnt, int n) {
  int wgl = blockIdx.x * 4 + (threadIdx.x >> 6);
  int lane = threadIdx.x & 63;
  int i0 = wgl * 64;
  if (i0 >= n) return;
  int i1 = min(i0 + 64, n);
  int cur = -1;
  float acc = 0.f, c = 0.f;
  for (int i = i0; i < i1; ++i) {
    int g = batch[i];
    if (g != cur) {
      if (cur >= 0) {
        atomicAdd(&pooled[cur * 64 + lane], acc);
        if (lane == 0) atomicAdd(&cnt[cur], c);
      }
      cur = g; acc = 0.f; c = 0.f;
    }
    acc += out2[(size_t)i * 64 + lane];
    c += 1.f;
  }
  if (cur >= 0) {
    atomicAdd(&pooled[cur * 64 + lane], acc);
    if (lane == 0) atomicAdd(&cnt[cur], c);
  }
}

// ---------- final: out[g,:] = (pooled[g,:]/cnt[g]) @ Pw + Pb ----------
__global__ __launch_bounds__(64) void k_final(const float* __restrict__ pooled,
                                              const float* __restrict__ cnt,
                                              const float* __restrict__ Pw,
                                              const float* __restrict__ Pb,
                                              float* __restrict__ out) {
  __shared__ float m[64];
  int g = blockIdx.x, o = threadIdx.x;
  m[o] = pooled[g * 64 + o] / fmaxf(cnt[g], 1.f);
  __syncthreads();
  float s = Pb[o];
#pragma unroll
  for (int c = 0; c < 64; ++c) s = fmaf(m[c], Pw[c * 64 + o], s);
  out[g * 64 + o] = s;
}

extern "C" void kernel_launch(void* const* d_in, const int* in_sizes, int n_in,
                              void* d_out, int out_size, void* d_ws, size_t ws_size,
                              hipStream_t stream) {
  const float* x         = (const float*)d_in[0];
  const int*   edge_index= (const int*)d_in[1];
  const float* edge_attr = (const float*)d_in[2];
  const int*   batch     = (const int*)d_in[3];
  const float* W1  = (const float*)d_in[4];
  const float* as1 = (const float*)d_in[5];
  const float* ad1 = (const float*)d_in[6];
  const float* We1 = (const float*)d_in[7];
  const float* ae1 = (const float*)d_in[8];
  const float* b1  = (const float*)d_in[9];
  const float* W2  = (const float*)d_in[10];
  const float* as2 = (const float*)d_in[11];
  const float* ad2 = (const float*)d_in[12];
  const float* We2 = (const float*)d_in[13];
  const float* ae2 = (const float*)d_in[14];
  const float* b2  = (const float*)d_in[15];
  const float* Pw  = (const float*)d_in[16];
  const float* Pb  = (const float*)d_in[17];

  const int N = in_sizes[0] / 128;
  const int E = in_sizes[1] / 2;
  const int G = out_size / 64;
  const int* srcI = edge_index;
  const int* dstI = edge_index + E;

  // ---- workspace layout (16B-aligned slots) ----
  float* ws = (float*)d_ws;
  size_t off = 0;
  auto alloc = [&](size_t elems) {
    float* p = ws + off;
    off += (elems + 3) & ~(size_t)3;
    return p;
  };
  int*   deg       = (int*)alloc(N);            // zeroed
  float* cnt       = alloc(G);                  // zeroed
  float* pooled    = alloc((size_t)G * 64);     // zeroed
  size_t zero_bytes = off * sizeof(float);
  int*   csr_off   = (int*)alloc(N + 1);
  int*   fill      = (int*)alloc(N);
  int*   csr_edges = (int*)alloc(E);
  int*   csr_src   = (int*)alloc(E);
  int*   csr_dst   = (int*)alloc(E);
  int*   bsum      = (int*)alloc(1024);
  float* loop_attr = alloc((size_t)N * 16);
  float* h         = alloc((size_t)N * 64);     // h1, reused as h2
  float* als       = alloc((size_t)N * 4);      // layer2 reuses first N
  float* ald       = alloc((size_t)N * 4);
  float* selfl     = alloc((size_t)N * 4);      // layer2 reuses first N
  float* elog      = alloc((size_t)E * 4);      // layer2 reuses first E
  float* outn      = alloc((size_t)N * 64);     // out1, reused as out2

  (void)ws_size; (void)n_in;
  hipMemsetAsync(d_ws, 0, zero_bytes, stream);

  const int ebl  = (E + 255) / 256;
  const int nb   = (N + 255) / 256;
  const int nbl4 = (N + 3) / 4;
  const int gemb = (N + 63) / 64;
  const int eN   = (E + N + 255) / 256;

  // CSR build (by dst)
  k_deg<<<ebl, 256, 0, stream>>>(dstI, deg, E);
  k_chunksum<<<nb, 256, 0, stream>>>(deg, bsum, N);
  k_bscan<<<1, 256, 0, stream>>>(bsum, nb, csr_off, N);
  k_chunkscan<<<nb, 256, 0, stream>>>(deg, bsum, csr_off, fill, N);
  k_scatter<<<ebl, 256, 0, stream>>>(dstI, srcI, fill, csr_edges, csr_src, csr_dst, E);
  k_loopattr<<<nbl4, 256, 0, stream>>>(csr_off, csr_edges, edge_attr, loop_attr, N);

  // layer 1
  k_gemm<128><<<gemb, 256, 0, stream>>>(x, W1, h, N);
  k_attn<4><<<(N * 4 + 255) / 256, 256, 0, stream>>>(h, as1, ad1, als, ald, N);
  k_elog1<<<eN, 256, 0, stream>>>(csr_edges, csr_src, csr_dst, edge_attr, loop_attr,
                                  We1, ae1, als, ald, elog, selfl, E, N);
  k_agg1<<<nbl4, 256, 0, stream>>>(csr_off, csr_src, elog, selfl, h, b1, outn, N);

  // layer 2 (reuses h/als/ald/selfl/elog slots; out2 overwrites out1)
  k_gemm<64><<<gemb, 256, 0, stream>>>(outn, W2, h, N);
  k_attn<1><<<(N + 255) / 256, 256, 0, stream>>>(h, as2, ad2, als, ald, N);
  k_elog2<<<eN, 256, 0, stream>>>(csr_edges, csr_src, csr_dst, edge_attr, loop_attr,
                                  We2, ae2, als, ald, elog, selfl, E, N);
  k_agg2<<<nbl4, 256, 0, stream>>>(csr_off, csr_src, elog, selfl, h, b2, outn, N);

  // pool + project
  k_pool<<<((N + 63) / 64 + 3) / 4, 256, 0, stream>>>(outn, batch, pooled, cnt, N);
  k_final<<<G, 64, 0, stream>>>(pooled, cnt, Pw, Pb, (float*)d_out);
}

// Round 4
// 341.215 us; speedup vs baseline: 6.0025x; 1.2507x over previous
//
#include <hip/hip_runtime.h>

#define LRELU(a) ((a) > 0.f ? (a) : 0.2f * (a))

// ---------- block-wide inclusive scan helper (256 threads, 4 waves) ----------
__device__ __forceinline__ int blockScanIncl256(int v, int* wl) {
  int t = threadIdx.x, lane = t & 63, w = t >> 6;
  int x = v;
#pragma unroll
  for (int o = 1; o < 64; o <<= 1) {
    int tmp = __shfl_up(x, (unsigned)o, 64);
    if (lane >= o) x += tmp;
  }
  if (lane == 63) wl[w] = x;
  __syncthreads();
  if (t == 0) {
    int s = 0;
#pragma unroll
    for (int j = 0; j < 4; ++j) { int tv = wl[j]; wl[j] = s; s += tv; }
  }
  __syncthreads();
  return x + wl[w];
}

// ---------- CSR build ----------
__global__ __launch_bounds__(256) void k_deg(const int* __restrict__ dst,
                                             int* __restrict__ deg, int E) {
  int e = blockIdx.x * 256 + threadIdx.x;
  if (e < E) atomicAdd(&deg[dst[e]], 1);
}

__global__ __launch_bounds__(256) void k_chunksum(const int* __restrict__ deg,
                                                  int* __restrict__ bsum, int n) {
  __shared__ int wl[4];
  int i = blockIdx.x * 256 + threadIdx.x;
  int v = (i < n) ? deg[i] : 0;
#pragma unroll
  for (int o = 1; o < 64; o <<= 1) v += __shfl_xor(v, o, 64);
  int lane = threadIdx.x & 63, w = threadIdx.x >> 6;
  if (lane == 0) wl[w] = v;
  __syncthreads();
  if (threadIdx.x == 0) bsum[blockIdx.x] = wl[0] + wl[1] + wl[2] + wl[3];
}

// single block; requires nb <= 256 (N <= 65536)
__global__ __launch_bounds__(256) void k_bscan(int* __restrict__ bsum, int nb,
                                               int* __restrict__ csr_off, int n) {
  __shared__ int wl[4];
  int t = threadIdx.x;
  int v = (t < nb) ? bsum[t] : 0;
  int incl = blockScanIncl256(v, wl);
  if (t < nb) bsum[t] = incl - v;  // exclusive block offsets
  if (t == 255) csr_off[n] = incl; // grand total
}

__global__ __launch_bounds__(256) void k_chunkscan(const int* __restrict__ deg,
                                                   const int* __restrict__ bsum,
                                                   int* __restrict__ csr_off,
                                                   int* __restrict__ fill, int n) {
  __shared__ int wl[4];
  int i = blockIdx.x * 256 + threadIdx.x;
  int v = (i < n) ? deg[i] : 0;
  int incl = blockScanIncl256(v, wl);
  int o = bsum[blockIdx.x] + incl - v;
  if (i < n) { csr_off[i] = o; fill[i] = o; }
}

__global__ __launch_bounds__(256) void k_scatter(const int* __restrict__ dst,
                                                 const int* __restrict__ src,
                                                 int* __restrict__ fill,
                                                 int* __restrict__ csr_edges,
                                                 int* __restrict__ csr_src,
                                                 int* __restrict__ csr_dst, int E) {
  int e = blockIdx.x * 256 + threadIdx.x;
  if (e < E) {
    int d = dst[e];
    int p = atomicAdd(&fill[d], 1);
    csr_edges[p] = e;
    csr_src[p] = src[e];
    csr_dst[p] = d;
  }
}

// ---------- self-loop edge attr = mean of incoming edge attrs ----------
// one wave per node: 64 lanes = 4 edges x 16 dims (coalesced 64B per edge)
__global__ __launch_bounds__(256) void k_loopattr(const int* __restrict__ csr_off,
                                                  const int* __restrict__ csr_edges,
                                                  const float* __restrict__ edge_attr,
                                                  float* __restrict__ loop_attr, int n) {
  int t = threadIdx.x, w = t >> 6, lane = t & 63;
  int node = blockIdx.x * 4 + w;
  if (node >= n) return;
  int sub = lane >> 4, k = lane & 15;
  int s0 = csr_off[node], s1 = csr_off[node + 1];
  float acc = 0.f;
  for (int i = s0 + sub; i < s1; i += 4)
    acc += edge_attr[(size_t)csr_edges[i] * 16 + k];
  acc += __shfl_xor(acc, 16, 64);
  acc += __shfl_xor(acc, 32, 64);
  if (sub == 0) loop_attr[node * 16 + k] = acc / fmaxf((float)(s1 - s0), 1.f);
}

// ---------- tiled f32 GEMM + fused attention-logit epilogue ----------
// H[b0:b0+64][0:64] = X[b0:b0+64][0:K] @ W[K][64]; als/ald = h . a per head.
// 256 threads = 16x16, each computes a 4x4 tile. X stride must equal K.
template <int K, int HH>
__global__ __launch_bounds__(256) void k_gemm(const float* __restrict__ X,
                                              const float* __restrict__ W,
                                              const float* __restrict__ a_s,
                                              const float* __restrict__ a_d,
                                              float* __restrict__ H,
                                              float* __restrict__ als,
                                              float* __restrict__ ald, int n) {
  __shared__ float Xs[64][K + 4];
  __shared__ float Ws[K][64];
  int t = threadIdx.x;
  int b0 = blockIdx.x * 64;
  for (int i = t; i < K * 64; i += 256) Ws[i >> 6][i & 63] = W[i];
  for (int i = t; i < 64 * K; i += 256) {
    int node = i / K, k = i % K;
    int r = b0 + node;
    Xs[node][k] = (r < n) ? X[(size_t)r * K + k] : 0.f;
  }
  __syncthreads();
  int tx = t & 15, ty = t >> 4;
  float acc[4][4] = {};
#pragma unroll 2
  for (int k4 = 0; k4 < K; k4 += 4) {
    float wvf[4][4];
#pragma unroll
    for (int j = 0; j < 4; ++j)
      *(float4*)&wvf[j][0] = *(const float4*)&Ws[k4 + j][tx * 4];
#pragma unroll
    for (int i = 0; i < 4; ++i) {
      float xvf[4];
      *(float4*)&xvf[0] = *(const float4*)&Xs[ty * 4 + i][k4];
#pragma unroll
      for (int kk = 0; kk < 4; ++kk)
#pragma unroll
        for (int j = 0; j < 4; ++j)
          acc[i][j] = fmaf(xvf[kk], wvf[kk][j], acc[i][j]);
    }
  }
#pragma unroll
  for (int i = 0; i < 4; ++i) {
    int node = b0 + ty * 4 + i;
    if (node < n)
      *(float4*)&H[(size_t)node * 64 + tx * 4] =
          make_float4(acc[i][0], acc[i][1], acc[i][2], acc[i][3]);
  }
  // ---- fused attention logits: als/ald[node*HH+head] ----
  constexpr int C = 64 / HH;     // channels per head
  constexpr int GL = C / 4;      // tx lanes per head group
  float asv[4], adv[4];
#pragma unroll
  for (int j = 0; j < 4; ++j) { asv[j] = a_s[tx * 4 + j]; adv[j] = a_d[tx * 4 + j]; }
#pragma unroll
  for (int i = 0; i < 4; ++i) {
    float ps = 0.f, pd = 0.f;
#pragma unroll
    for (int j = 0; j < 4; ++j) {
      ps = fmaf(acc[i][j], asv[j], ps);
      pd = fmaf(acc[i][j], adv[j], pd);
    }
#pragma unroll
    for (int o = 1; o < GL; o <<= 1) {
      ps += __shfl_xor(ps, o, 64);
      pd += __shfl_xor(pd, o, 64);
    }
    int node = b0 + ty * 4 + i;
    if (node < n && (tx & (GL - 1)) == 0) {
      int head = tx / GL;
      als[(size_t)node * HH + head] = ps;
      ald[(size_t)node * HH + head] = pd;
    }
  }
}

// ---------- CSR-ordered fused logits, layer 1: elog[i][h]=LRELU(als[s]+ald[d]+ea@wa)
__global__ __launch_bounds__(256) void k_elog1(const int* __restrict__ csr_edges,
                                               const int* __restrict__ csr_src,
                                               const int* __restrict__ csr_dst,
                                               const float* __restrict__ edge_attr,
                                               const float* __restrict__ loop_attr,
                                               const float* __restrict__ We1,
                                               const float* __restrict__ ae1,
                                               const float* __restrict__ als,
                                               const float* __restrict__ ald,
                                               float* __restrict__ elog,
                                               float* __restrict__ selfl, int E, int n) {
  __shared__ float wa[64];  // [k*4+h] = sum_c We1[k,h*16+c]*ae1[h,c]
  int t = threadIdx.x;
  if (t < 64) {
    int k = t >> 2, hh = t & 3;
    float s = 0.f;
#pragma unroll
    for (int c = 0; c < 16; ++c) s = fmaf(We1[k * 64 + hh * 16 + c], ae1[hh * 16 + c], s);
    wa[t] = s;
  }
  __syncthreads();
  int idx = blockIdx.x * 256 + t;
  if (idx >= E + n) return;
  int s, d;
  const float* ea;
  if (idx < E) {
    s = csr_src[idx]; d = csr_dst[idx];
    ea = edge_attr + (size_t)csr_edges[idx] * 16;
  } else {
    s = d = idx - E;
    ea = loop_attr + (size_t)s * 16;
  }
  float4 av = *(const float4*)(als + (size_t)s * 4);
  float4 dv = *(const float4*)(ald + (size_t)d * 4);
  float l0 = av.x + dv.x, l1 = av.y + dv.y, l2 = av.z + dv.z, l3 = av.w + dv.w;
#pragma unroll
  for (int k = 0; k < 16; ++k) {
    float v = ea[k];
    l0 = fmaf(v, wa[k * 4 + 0], l0);
    l1 = fmaf(v, wa[k * 4 + 1], l1);
    l2 = fmaf(v, wa[k * 4 + 2], l2);
    l3 = fmaf(v, wa[k * 4 + 3], l3);
  }
  float4 r = make_float4(LRELU(l0), LRELU(l1), LRELU(l2), LRELU(l3));
  if (idx < E) *(float4*)(elog + (size_t)idx * 4) = r;
  else *(float4*)(selfl + (size_t)(idx - E) * 4) = r;
}

// ---------- layer 1 aggregation ----------
// phase 1: exact segment max+denom from sequential elog reads (lanes = 16 edges x 4 heads)
// phase 2: batched (8-deep, double-buffered) h gathers, pure exp*fma accumulation
__global__ __launch_bounds__(256) void k_agg1(const int* __restrict__ csr_off,
                                              const int* __restrict__ csr_src,
                                              const float* __restrict__ elog,
                                              const float* __restrict__ selfl,
                                              const float* __restrict__ h1,
                                              const float* __restrict__ b1,
                                              float* __restrict__ out1, int n) {
  int t = threadIdx.x, w = t >> 6, lane = t & 63;
  int node = blockIdx.x * 4 + w;
  if (node >= n) return;
  int s0 = csr_off[node], s1 = csr_off[node + 1];
  int nit = s1 - s0;
  // ---- phase 1 ----
  int h4 = lane & 3;
  float sl4 = selfl[node * 4 + h4];
  float m = sl4;
  for (int i = s0 + (lane >> 2); i < s1; i += 16)
    m = fmaxf(m, elog[(size_t)i * 4 + h4]);
#pragma unroll
  for (int o = 4; o < 64; o <<= 1) m = fmaxf(m, __shfl_xor(m, o, 64));
  float den = ((lane >> 2) == 0) ? __expf(sl4 - m) : 0.f;
  for (int i = s0 + (lane >> 2); i < s1; i += 16)
    den += __expf(elog[(size_t)i * 4 + h4] - m);
#pragma unroll
  for (int o = 4; o < 64; o <<= 1) den += __shfl_xor(den, o, 64);
  int head = lane >> 4;  // head in channel layout
  float m_ch = __shfl(m, head, 64);
  float rd_ch = 1.f / __shfl(den, head, 64);
  float sl_ch = __shfl(sl4, head, 64);
  float acc = __expf(sl_ch - m_ch) * h1[(size_t)node * 64 + lane];
  // ---- phase 2 ----
  if (nit > 0) {
    int nb = (nit + 7) >> 3;
    int laneE = lane & 7, laneB = (lane >> 2) & 7, laneH = lane & 3;
    int sv; float ev;
    float bufA[8], bufB[8];
    {
      int i1 = min(s0 + laneE, s1 - 1);
      sv = csr_src[i1];
      int i2 = min(s0 + laneB, s1 - 1);
      ev = elog[(size_t)i2 * 4 + laneH];
    }
#pragma unroll
    for (int j = 0; j < 8; ++j)
      bufA[j] = h1[(size_t)__shfl(sv, j, 64) * 64 + lane];
    for (int b = 0; b < nb; ++b) {
      int svN = 0; float evN = 0.f;
      bool pf = (b + 1 < nb);
      if (pf) {
        int base = s0 + (b + 1) * 8;
        int i1 = min(base + laneE, s1 - 1);
        svN = csr_src[i1];
        int i2 = min(base + laneB, s1 - 1);
        evN = elog[(size_t)i2 * 4 + laneH];
#pragma unroll
        for (int j = 0; j < 8; ++j)
          bufB[j] = h1[(size_t)__shfl(svN, j, 64) * 64 + lane];
      }
      int rem = nit - b * 8;
#pragma unroll
      for (int j = 0; j < 8; ++j) {
        float aj = __shfl(ev, j * 4 + head, 64);
        float ex = (j < rem) ? __expf(aj - m_ch) : 0.f;
        acc = fmaf(ex, bufA[j], acc);
      }
      if (pf) {
#pragma unroll
        for (int j = 0; j < 8; ++j) bufA[j] = bufB[j];
        sv = svN; ev = evN;
      }
    }
  }
  float r = acc * rd_ch + b1[lane];
  out1[(size_t)node * 64 + lane] = r > 0.f ? r : expm1f(r);  // ELU fused
}

// ---------- CSR-ordered fused logits, layer 2 (H=1, scalar) ----------
__global__ __launch_bounds__(256) void k_elog2(const int* __restrict__ csr_edges,
                                               const int* __restrict__ csr_src,
                                               const int* __restrict__ csr_dst,
                                               const float* __restrict__ edge_attr,
                                               const float* __restrict__ loop_attr,
                                               const float* __restrict__ We2,
                                               const float* __restrict__ ae2,
                                               const float* __restrict__ als,
                                               const float* __restrict__ ald,
                                               float* __restrict__ elog,
                                               float* __restrict__ selfl, int E, int n) {
  __shared__ float wa[16];
  int t = threadIdx.x;
  if (t < 16) {
    float s = 0.f;
#pragma unroll
    for (int c = 0; c < 64; ++c) s = fmaf(We2[t * 64 + c], ae2[c], s);
    wa[t] = s;
  }
  __syncthreads();
  int idx = blockIdx.x * 256 + t;
  if (idx >= E + n) return;
  int s, d;
  const float* ea;
  if (idx < E) {
    s = csr_src[idx]; d = csr_dst[idx];
    ea = edge_attr + (size_t)csr_edges[idx] * 16;
  } else {
    s = d = idx - E;
    ea = loop_attr + (size_t)s * 16;
  }
  float lg = als[s] + ald[d];
#pragma unroll
  for (int k = 0; k < 16; ++k) lg = fmaf(ea[k], wa[k], lg);
  lg = LRELU(lg);
  if (idx < E) elog[idx] = lg;
  else selfl[idx - E] = lg;
}

// ---------- layer 2 aggregation (scalar head) ----------
__global__ __launch_bounds__(256) void k_agg2(const int* __restrict__ csr_off,
                                              const int* __restrict__ csr_src,
                                              const float* __restrict__ elog,
                                              const float* __restrict__ selfl,
                                              const float* __restrict__ h2,
                                              const float* __restrict__ b2,
                                              float* __restrict__ out2, int n) {
  int t = threadIdx.x, w = t >> 6, lane = t & 63;
  int node = blockIdx.x * 4 + w;
  if (node >= n) return;
  int s0 = csr_off[node], s1 = csr_off[node + 1];
  int nit = s1 - s0;
  // ---- phase 1 ----
  float sl = selfl[node];
  float m = sl;
  for (int i = s0 + lane; i < s1; i += 64) m = fmaxf(m, elog[i]);
#pragma unroll
  for (int o = 1; o < 64; o <<= 1) m = fmaxf(m, __shfl_xor(m, o, 64));
  float den = (lane == 0) ? __expf(sl - m) : 0.f;
  for (int i = s0 + lane; i < s1; i += 64) den += __expf(elog[i] - m);
#pragma unroll
  for (int o = 1; o < 64; o <<= 1) den += __shfl_xor(den, o, 64);
  float rd = 1.f / den;
  float acc = __expf(sl - m) * h2[(size_t)node * 64 + lane];
  // ---- phase 2 ----
  if (nit > 0) {
    int nb = (nit + 7) >> 3;
    int laneE = lane & 7;
    int sv; float ev;
    {
      int i1 = min(s0 + laneE, s1 - 1);
      sv = csr_src[i1];
      ev = elog[i1];
    }
    float bufA[8], bufB[8];
#pragma unroll
    for (int j = 0; j < 8; ++j)
      bufA[j] = h2[(size_t)__shfl(sv, j, 64) * 64 + lane];
    for (int b = 0; b < nb; ++b) {
      int svN = 0; float evN = 0.f;
      bool pf = (b + 1 < nb);
      if (pf) {
        int i1 = min(s0 + (b + 1) * 8 + laneE, s1 - 1);
        svN = csr_src[i1];
        evN = elog[i1];
#pragma unroll
        for (int j = 0; j < 8; ++j)
          bufB[j] = h2[(size_t)__shfl(svN, j, 64) * 64 + lane];
      }
      int rem = nit - b * 8;
#pragma unroll
      for (int j = 0; j < 8; ++j) {
        float aj = __shfl(ev, j, 64);
        float ex = (j < rem) ? __expf(aj - m) : 0.f;
        acc = fmaf(ex, bufA[j], acc);
      }
      if (pf) {
#pragma unroll
        for (int j = 0; j < 8; ++j) bufA[j] = bufB[j];
        sv = svN; ev = evN;
      }
    }
  }
  out2[(size_t)node * 64 + lane] = acc * rd + b2[lane];  // H2=1: mean = identity
}

// ---------- pooling: sorted batch, wave handles 64 consecutive nodes ----------
__global__ __launch_bounds__(256) void k_pool(const float* __restrict__ out2,
                                              const int* __restrict__ batch,
                                              float* __restrict__ pooled,
                                              float* __restrict__ cnt, int n) {
  int wgl = blockIdx.x * 4 + (threadIdx.x >> 6);
  int lane = threadIdx.x & 63;
  int i0 = wgl * 64;
  if (i0 >= n) return;
  int i1 = min(i0 + 64, n);
  int cur = -1;
  float acc = 0.f, c = 0.f;
  for (int i = i0; i < i1; ++i) {
    int g = batch[i];
    if (g != cur) {
      if (cur >= 0) {
        atomicAdd(&pooled[cur * 64 + lane], acc);
        if (lane == 0) atomicAdd(&cnt[cur], c);
      }
      cur = g; acc = 0.f; c = 0.f;
    }
    acc += out2[(size_t)i * 64 + lane];
    c += 1.f;
  }
  if (cur >= 0) {
    atomicAdd(&pooled[cur * 64 + lane], acc);
    if (lane == 0) atomicAdd(&cnt[cur], c);
  }
}

// ---------- final: out[g,:] = (pooled[g,:]/cnt[g]) @ Pw + Pb ----------
__global__ __launch_bounds__(64) void k_final(const float* __restrict__ pooled,
                                              const float* __restrict__ cnt,
                                              const float* __restrict__ Pw,
                                              const float* __restrict__ Pb,
                                              float* __restrict__ out) {
  __shared__ float m[64];
  int g = blockIdx.x, o = threadIdx.x;
  m[o] = pooled[g * 64 + o] / fmaxf(cnt[g], 1.f);
  __syncthreads();
  float s = Pb[o];
#pragma unroll
  for (int c = 0; c < 64; ++c) s = fmaf(m[c], Pw[c * 64 + o], s);
  out[g * 64 + o] = s;
}

extern "C" void kernel_launch(void* const* d_in, const int* in_sizes, int n_in,
                              void* d_out, int out_size, void* d_ws, size_t ws_size,
                              hipStream_t stream) {
  const float* x         = (const float*)d_in[0];
  const int*   edge_index= (const int*)d_in[1];
  const float* edge_attr = (const float*)d_in[2];
  const int*   batch     = (const int*)d_in[3];
  const float* W1  = (const float*)d_in[4];
  const float* as1 = (const float*)d_in[5];
  const float* ad1 = (const float*)d_in[6];
  const float* We1 = (const float*)d_in[7];
  const float* ae1 = (const float*)d_in[8];
  const float* b1  = (const float*)d_in[9];
  const float* W2  = (const float*)d_in[10];
  const float* as2 = (const float*)d_in[11];
  const float* ad2 = (const float*)d_in[12];
  const float* We2 = (const float*)d_in[13];
  const float* ae2 = (const float*)d_in[14];
  const float* b2  = (const float*)d_in[15];
  const float* Pw  = (const float*)d_in[16];
  const float* Pb  = (const float*)d_in[17];

  const int N = in_sizes[0] / 128;
  const int E = in_sizes[1] / 2;
  const int G = out_size / 64;
  const int* srcI = edge_index;
  const int* dstI = edge_index + E;

  // ---- workspace layout (16B-aligned slots) ----
  float* ws = (float*)d_ws;
  size_t off = 0;
  auto alloc = [&](size_t elems) {
    float* p = ws + off;
    off += (elems + 3) & ~(size_t)3;
    return p;
  };
  int*   deg       = (int*)alloc(N);            // zeroed
  float* cnt       = alloc(G);                  // zeroed
  float* pooled    = alloc((size_t)G * 64);     // zeroed
  size_t zero_bytes = off * sizeof(float);
  int*   csr_off   = (int*)alloc(N + 1);
  int*   fill      = (int*)alloc(N);
  int*   csr_edges = (int*)alloc(E);
  int*   csr_src   = (int*)alloc(E);
  int*   csr_dst   = (int*)alloc(E);
  int*   bsum      = (int*)alloc(1024);
  float* loop_attr = alloc((size_t)N * 16);
  float* h         = alloc((size_t)N * 64);     // h1, reused as h2
  float* als       = alloc((size_t)N * 4);      // layer2 reuses first N
  float* ald       = alloc((size_t)N * 4);
  float* selfl     = alloc((size_t)N * 4);      // layer2 reuses first N
  float* elog      = alloc((size_t)E * 4);      // layer2 reuses first E
  float* outn      = alloc((size_t)N * 64);     // out1, reused as out2

  (void)ws_size; (void)n_in;
  hipMemsetAsync(d_ws, 0, zero_bytes, stream);

  const int ebl  = (E + 255) / 256;
  const int nb   = (N + 255) / 256;
  const int nbl4 = (N + 3) / 4;
  const int gemb = (N + 63) / 64;
  const int eN   = (E + N + 255) / 256;

  // CSR build (by dst)
  k_deg<<<ebl, 256, 0, stream>>>(dstI, deg, E);
  k_chunksum<<<nb, 256, 0, stream>>>(deg, bsum, N);
  k_bscan<<<1, 256, 0, stream>>>(bsum, nb, csr_off, N);
  k_chunkscan<<<nb, 256, 0, stream>>>(deg, bsum, csr_off, fill, N);
  k_scatter<<<ebl, 256, 0, stream>>>(dstI, srcI, fill, csr_edges, csr_src, csr_dst, E);
  k_loopattr<<<nbl4, 256, 0, stream>>>(csr_off, csr_edges, edge_attr, loop_attr, N);

  // layer 1
  k_gemm<128, 4><<<gemb, 256, 0, stream>>>(x, W1, as1, ad1, h, als, ald, N);
  k_elog1<<<eN, 256, 0, stream>>>(csr_edges, csr_src, csr_dst, edge_attr, loop_attr,
                                  We1, ae1, als, ald, elog, selfl, E, N);
  k_agg1<<<nbl4, 256, 0, stream>>>(csr_off, csr_src, elog, selfl, h, b1, outn, N);

  // layer 2 (reuses h/als/ald/selfl/elog slots; out2 overwrites out1)
  k_gemm<64, 1><<<gemb, 256, 0, stream>>>(outn, W2, as2, ad2, h, als, ald, N);
  k_elog2<<<eN, 256, 0, stream>>>(csr_edges, csr_src, csr_dst, edge_attr, loop_attr,
                                  We2, ae2, als, ald, elog, selfl, E, N);
  k_agg2<<<nbl4, 256, 0, stream>>>(csr_off, csr_src, elog, selfl, h, b2, outn, N);

  // pool + project
  k_pool<<<((N + 63) / 64 + 3) / 4, 256, 0, stream>>>(outn, batch, pooled, cnt, N);
  k_final<<<G, 64, 0, stream>>>(pooled, cnt, Pw, Pb, (float*)d_out);
}